// Round 9
// baseline (53.110 us; speedup 1.0000x reference)
//
#include <hip/hip_runtime.h>
#include <hip/hip_fp16.h>

// Problem constants
#define B_TOT 65536
#define I_DIM 128
#define N_DIM 256
#define NTHR  256
#define ROWS  16     // batch rows per wave

typedef __attribute__((ext_vector_type(8))) _Float16 half8;
typedef __attribute__((ext_vector_type(4))) _Float16 half4;
typedef __attribute__((ext_vector_type(4))) float    f32x4;

__device__ inline float fast_exp2(float x) {
#if __has_builtin(__builtin_amdgcn_exp2f)
  return __builtin_amdgcn_exp2f(x);
#else
  return exp2f(x);
#endif
}
__device__ inline float fast_rcp(float x) {
#if __has_builtin(__builtin_amdgcn_rcpf)
  return __builtin_amdgcn_rcpf(x);
#else
  return 1.0f / x;
#endif
}

// ws layout:
//   [0, 65536)      : W_in as fp16, row-major [256][128] linear (L2-resident)
//   [65536, +4096)  : P4[256] float4 = {wm, bias, nsl, A} per neuron
//   [69632, +1024)  : PT[256] float  = -1/tau per neuron
__global__ void prep_kernel(const float* __restrict__ W_in, const float* __restrict__ w_rec,
                            const void* __restrict__ mask, const float* __restrict__ bias,
                            const float* __restrict__ tau, const float* __restrict__ Aamp,
                            const float* __restrict__ sigma, char* __restrict__ ws) {
  __shared__ int flag;
  const int t = threadIdx.x;

  if (blockIdx.x == 0) {
    // ---- mask dtype detection: reads stay within 256 bytes under either layout ----
    if (t == 0) flag = 0;
    __syncthreads();
    if (t < 64) {
      int w = ((const int*)mask)[t];
      if (w != 0 && w != 1) atomicOr(&flag, 1);
    }
    __syncthreads();
    const bool as_bytes = (flag != 0);
    const int nn = t;  // one neuron per thread
    float mv = as_bytes ? (float)(((const unsigned char*)mask)[nn])
                        : (float)(((const int*)mask)[nn]);
    float4 p4;
    p4.x = w_rec[nn] * mv;                          // wm (sparsity-masked)
    p4.y = bias[nn];                                 // bias
    p4.z = -sigma[nn] * 1.44269504088896340736f;     // -sigma*log2(e)
    p4.w = Aamp[nn];                                 // A
    ((float4*)(ws + 65536))[nn] = p4;
    ((float*)(ws + 69632))[nn]  = -1.0f / tau[nn];   // -1/tau
  }

  // ---- W_in fp32 -> fp16, linear row-major, coalesced ----
  int f4 = blockIdx.x * NTHR + t;            // 0..8191 float4s (256*128/4)
  float4 v = ((const float4*)W_in)[f4];
  half4 hv;
  hv[0] = (_Float16)v.x; hv[1] = (_Float16)v.y;
  hv[2] = (_Float16)v.z; hv[3] = (_Float16)v.w;
  ((half4*)ws)[f4] = hv;
}

// RK4 for one element. dx/dt = -x/tau + sigmoid(sigma*(ic + x*wm + b))*(A - x)
__device__ inline float rk4_one(float ic, float bi, float wm, float nsl,
                                float Aa, float nt, float h0) {
  const float icb = ic + bi;
  auto ode = [&](float s) {
    float tot = fmaf(s, wm, icb);
    float e   = fast_exp2(nsl * tot);         // exp(-sigma*tot)
    float f   = fast_rcp(1.0f + e);           // sigmoid
    return fmaf(f, Aa - s, s * nt);
  };
  float k1 = ode(h0);
  float k2 = ode(fmaf(0.5f, k1, h0));
  float k3 = ode(fmaf(0.5f, k2, h0));
  float k4 = ode(h0 + k3);
  return fmaf(fmaf(2.0f, k2 + k3, k1 + k4), 0.16666666666666666f, h0);
}

// Barrier-free wave-streaming: no LDS, no __syncthreads. Each wave owns 16
// batch rows end-to-end; waves drift freely so memory and compute overlap
// chip-wide instead of phase-locking.
__launch_bounds__(NTHR, 6)
__global__ void liquid_kernel(const float* __restrict__ x, const float* __restrict__ h,
                              const char* __restrict__ ws, float* __restrict__ out) {
  const int t    = threadIdx.x;
  const int lane = t & 63;
  const int lr   = lane & 15;   // A-frag row (batch) / B-frag col (neuron)
  const int lk   = lane >> 4;   // k-group; C row-group
  const int wid  = blockIdx.x * (NTHR / 64) + (t >> 6);
  const int r0   = wid * ROWS;

  // ---- x A-fragments: lane holds x[r0+lr][kc*32 + lk*8 .. +8], fp32->fp16.
  //      8 independent global loads issued up front, converted in regs. ----
  const float* xrow = x + (size_t)(r0 + lr) * I_DIM + lk * 8;
  f32x4 xa[4], xb[4];
#pragma unroll
  for (int kc = 0; kc < 4; ++kc) {
    xa[kc] = *(const f32x4*)(xrow + kc * 32);
    xb[kc] = *(const f32x4*)(xrow + kc * 32 + 4);
  }
  half8 xf[4];
#pragma unroll
  for (int kc = 0; kc < 4; ++kc) {
    half8 v;
    v[0] = (_Float16)xa[kc][0]; v[1] = (_Float16)xa[kc][1];
    v[2] = (_Float16)xa[kc][2]; v[3] = (_Float16)xa[kc][3];
    v[4] = (_Float16)xb[kc][0]; v[5] = (_Float16)xb[kc][1];
    v[6] = (_Float16)xb[kc][2]; v[7] = (_Float16)xb[kc][3];
    xf[kc] = v;
  }

  const char*   wg = ws;                          // W fp16 [256][128]
  const float4* P4 = (const float4*)(ws + 65536); // {wm,bias,nsl,A}
  const float*  PT = (const float*)(ws + 69632);  // -1/tau
  const int nst = wid & 15;                       // start-offset stagger (de-phase)
  const size_t rowbase = (size_t)(r0 + lk * 4) * N_DIM + lr;  // + n*16 + r*256

  // ---- depth-1 prefetch of h/params for the first neuron tile ----
  float  hcur[4]; float4 p4c; float ntc;
  {
    const int n = nst;
    const size_t hb = rowbase + n * 16;
#pragma unroll
    for (int r = 0; r < 4; ++r) hcur[r] = h[hb + (size_t)r * N_DIM];
    p4c = P4[n * 16 + lr];
    ntc = PT[n * 16 + lr];
  }

#pragma unroll
  for (int i = 0; i < 16; ++i) {
    const int n  = (nst + i) & 15;
    const int nn = n * 16 + lr;

    // issue next tile's h/param loads before compute (latency hides under RK4)
    float hnxt[4]; float4 p4n; float ntn;
    if (i < 15) {
      const int n2 = (nst + i + 1) & 15;
      const size_t hb2 = rowbase + n2 * 16;
#pragma unroll
      for (int r = 0; r < 4; ++r) hnxt[r] = h[hb2 + (size_t)r * N_DIM];
      p4n = P4[n2 * 16 + lr];
      ntn = PT[n2 * 16 + lr];
    }

    // ---- GEMM for this neuron tile: ic[16 rows][16 neurons] ----
    const char* wrow = wg + (size_t)nn * 256;     // W row = neuron nn
    f32x4 acc = {0.0f, 0.0f, 0.0f, 0.0f};
#pragma unroll
    for (int kc = 0; kc < 4; ++kc) {
      half8 wf = *(const half8*)(wrow + kc * 64 + lk * 16);
      acc = __builtin_amdgcn_mfma_f32_16x16x32_f16(xf[kc], wf, acc, 0, 0, 0);
    }

    // ---- RK4 on the 4 elements this lane owns; stream out ----
    const size_t ob = rowbase + n * 16;
#pragma unroll
    for (int r = 0; r < 4; ++r) {
      float o = rk4_one(acc[r], p4c.y, p4c.x, p4c.z, p4c.w, ntc, hcur[r]);
      __builtin_nontemporal_store(o, out + ob + (size_t)r * N_DIM);
    }

    if (i < 15) {
#pragma unroll
      for (int r = 0; r < 4; ++r) hcur[r] = hnxt[r];
      p4c = p4n; ntc = ntn;
    }
  }
}

extern "C" void kernel_launch(void* const* d_in, const int* in_sizes, int n_in,
                              void* d_out, int out_size, void* d_ws, size_t ws_size,
                              hipStream_t stream) {
  const float* x     = (const float*)d_in[0];
  const float* h     = (const float*)d_in[1];
  const float* W_in  = (const float*)d_in[2];
  const float* w_rec = (const float*)d_in[3];
  const void*  mask  = d_in[4];
  const float* bias  = (const float*)d_in[5];
  const float* tau   = (const float*)d_in[6];
  const float* A     = (const float*)d_in[7];
  const float* sigma = (const float*)d_in[8];
  float* out = (float*)d_out;
  char*  ws  = (char*)d_ws;

  prep_kernel<<<32, NTHR, 0, stream>>>(W_in, w_rec, mask, bias, tau, A, sigma, ws);
  liquid_kernel<<<B_TOT / (ROWS * (NTHR / 64)), NTHR, 0, stream>>>(x, h, ws, out);
}